// Round 2
// baseline (5642.346 us; speedup 1.0000x reference)
//
#include <hip/hip_runtime.h>

#define NSITES 500000
#define KOFF   27
#define RPAIR  250000
#define CIN    16
#define COUT   16

// ---------------------------------------------------------------------------
// Kernel 1: out[row][c] = bias[c]  (d_out is poisoned 0xAA before every call)
// ---------------------------------------------------------------------------
__global__ __launch_bounds__(256) void init_bias_kernel(
    const float* __restrict__ bias, float* __restrict__ out, int n_rows)
{
    int row = blockIdx.x * blockDim.x + threadIdx.x;
    if (row >= n_rows) return;
    const float4* b4 = (const float4*)bias;
    float4 b0 = b4[0], b1 = b4[1], b2 = b4[2], b3 = b4[3];
    float4* o = (float4*)(out + (size_t)row * COUT);
    o[0] = b0; o[1] = b1; o[2] = b2; o[3] = b3;
}

// ---------------------------------------------------------------------------
// Kernel 2: for each pair p=(k,r): out[rules_out[p]] += features[rules_in[p]] @ W[k]
// Grid: (ceil(R/256), K) so k is block-uniform -> W[k] staged in LDS (1 KB).
// One thread per pair. Fully unrolled 16x16 mat-vec, 16 atomic f32 adds.
// (Resubmit of round-1 baseline: previous round was an infra failure,
//  kernel never executed.)
// ---------------------------------------------------------------------------
__device__ inline void fma4(float4& a, float s, const float4 w) {
    a.x = fmaf(s, w.x, a.x);
    a.y = fmaf(s, w.y, a.y);
    a.z = fmaf(s, w.z, a.z);
    a.w = fmaf(s, w.w, a.w);
}

__global__ __launch_bounds__(256) void scatter_conv_kernel(
    const float* __restrict__ features,
    const float* __restrict__ weight,
    const int*   __restrict__ rules_in,
    const int*   __restrict__ rules_out,
    float*       __restrict__ out)
{
    __shared__ float wlds[CIN * COUT];
    const int k   = blockIdx.y;
    const int tid = threadIdx.x;

    // 256 threads stage 256 floats of W[k] (layout [c_in][c_out])
    wlds[tid] = weight[k * CIN * COUT + tid];
    __syncthreads();

    const int r = blockIdx.x * blockDim.x + tid;
    if (r >= RPAIR) return;
    const int p = k * RPAIR + r;

    const int in_idx  = rules_in[p];
    const int out_idx = rules_out[p];

    const float4* f4 = (const float4*)(features + (size_t)in_idx * CIN);
    const float4 f0 = f4[0], f1 = f4[1], f2 = f4[2], f3 = f4[3];

    const float4* w4 = (const float4*)wlds;
    float4 a0 = make_float4(0.f, 0.f, 0.f, 0.f);
    float4 a1 = a0, a2 = a0, a3 = a0;

    // acc[co] += f[c] * W[c][co], fully unrolled, static indices only
#define CSTEP(fc, c)                       \
    {                                      \
        fma4(a0, (fc), w4[(c) * 4 + 0]);   \
        fma4(a1, (fc), w4[(c) * 4 + 1]);   \
        fma4(a2, (fc), w4[(c) * 4 + 2]);   \
        fma4(a3, (fc), w4[(c) * 4 + 3]);   \
    }
    CSTEP(f0.x,  0) CSTEP(f0.y,  1) CSTEP(f0.z,  2) CSTEP(f0.w,  3)
    CSTEP(f1.x,  4) CSTEP(f1.y,  5) CSTEP(f1.z,  6) CSTEP(f1.w,  7)
    CSTEP(f2.x,  8) CSTEP(f2.y,  9) CSTEP(f2.z, 10) CSTEP(f2.w, 11)
    CSTEP(f3.x, 12) CSTEP(f3.y, 13) CSTEP(f3.z, 14) CSTEP(f3.w, 15)
#undef CSTEP

    float* op = out + (size_t)out_idx * COUT;
    // HW global_atomic_add_f32 (device scope); values ~O(1), no denormal risk
    unsafeAtomicAdd(op +  0, a0.x);
    unsafeAtomicAdd(op +  1, a0.y);
    unsafeAtomicAdd(op +  2, a0.z);
    unsafeAtomicAdd(op +  3, a0.w);
    unsafeAtomicAdd(op +  4, a1.x);
    unsafeAtomicAdd(op +  5, a1.y);
    unsafeAtomicAdd(op +  6, a1.z);
    unsafeAtomicAdd(op +  7, a1.w);
    unsafeAtomicAdd(op +  8, a2.x);
    unsafeAtomicAdd(op +  9, a2.y);
    unsafeAtomicAdd(op + 10, a2.z);
    unsafeAtomicAdd(op + 11, a2.w);
    unsafeAtomicAdd(op + 12, a3.x);
    unsafeAtomicAdd(op + 13, a3.y);
    unsafeAtomicAdd(op + 14, a3.z);
    unsafeAtomicAdd(op + 15, a3.w);
}

extern "C" void kernel_launch(void* const* d_in, const int* in_sizes, int n_in,
                              void* d_out, int out_size, void* d_ws, size_t ws_size,
                              hipStream_t stream)
{
    const float* features  = (const float*)d_in[0];
    const float* weight    = (const float*)d_in[1];
    const float* bias      = (const float*)d_in[2];
    const int*   rules_in  = (const int*)d_in[3];
    const int*   rules_out = (const int*)d_in[4];
    float*       out       = (float*)d_out;

    // 1) out = bias (must run every call; d_out is re-poisoned)
    {
        dim3 grid((NSITES + 255) / 256);
        init_bias_kernel<<<grid, 256, 0, stream>>>(bias, out, NSITES);
    }
    // 2) scatter-accumulate all K*R pairs
    {
        dim3 grid((RPAIR + 255) / 256, KOFF);
        scatter_conv_kernel<<<grid, 256, 0, stream>>>(features, weight,
                                                      rules_in, rules_out, out);
    }
}

// Round 3
// 1075.126 us; speedup vs baseline: 5.2481x; 5.2481x over previous
//
#include <hip/hip_runtime.h>

#define NSITES 500000
#define KOFF   27
#define RPAIR  250000
#define KR     (KOFF * RPAIR)       // 6,750,000 pairs
#define CIN    16
#define COUT   16

#define SCAN_B 1024
#define NBLK   ((NSITES + SCAN_B - 1) / SCAN_B)   // 489

// LDS weight layout: [k][260] floats; stride 260 (=1040B) keeps float4
// alignment (1040%16==0) and spreads k bases over 8 LDS bank offsets
// (260*k mod 32 = 4k mod 32) to cap ds_read_b128 conflicts.
#define WSTRIDE 260

// ---------------- workspace layout (int32 slots) ----------------
// counts   [0,        N)
// starts   [N,       2N)
// cursor   [2N,      3N)
// blocksum [3N,      3N+512)
// blockoff [3N+512,  3N+1024)
// csr      [3N+1024, 3N+1024+KR)

// ---------------------------------------------------------------------------
// Pass 1: histogram of rules_out into counts
// ---------------------------------------------------------------------------
__global__ __launch_bounds__(256) void histogram_kernel(
    const int* __restrict__ rules_out, int* __restrict__ counts)
{
    const int k = blockIdx.y;
    const int r = blockIdx.x * blockDim.x + threadIdx.x;
    if (r >= RPAIR) return;
    atomicAdd(counts + rules_out[k * RPAIR + r], 1);
}

// ---------------------------------------------------------------------------
// Pass 2: exclusive prefix scan of counts -> starts (3 kernels)
// ---------------------------------------------------------------------------
__global__ __launch_bounds__(SCAN_B) void scan_blocks_kernel(
    const int* __restrict__ counts, int* __restrict__ starts,
    int* __restrict__ blocksum)
{
    __shared__ int s[SCAN_B];
    const int g = blockIdx.x * SCAN_B + threadIdx.x;
    const int v = (g < NSITES) ? counts[g] : 0;
    s[threadIdx.x] = v;
    __syncthreads();
    for (int off = 1; off < SCAN_B; off <<= 1) {
        int t = (threadIdx.x >= off) ? s[threadIdx.x - off] : 0;
        __syncthreads();
        s[threadIdx.x] += t;
        __syncthreads();
    }
    if (g < NSITES) starts[g] = s[threadIdx.x] - v;   // exclusive
    if (threadIdx.x == SCAN_B - 1) blocksum[blockIdx.x] = s[threadIdx.x];
}

__global__ __launch_bounds__(SCAN_B) void scan_totals_kernel(
    const int* __restrict__ blocksum, int* __restrict__ blockoff)
{
    __shared__ int s[SCAN_B];
    const int i = threadIdx.x;
    const int v = (i < NBLK) ? blocksum[i] : 0;
    s[i] = v;
    __syncthreads();
    for (int off = 1; off < SCAN_B; off <<= 1) {
        int t = (i >= off) ? s[i - off] : 0;
        __syncthreads();
        s[i] += t;
        __syncthreads();
    }
    if (i < NBLK) blockoff[i] = s[i] - v;             // exclusive
}

__global__ __launch_bounds__(SCAN_B) void add_base_kernel(
    int* __restrict__ starts, const int* __restrict__ blockoff,
    int* __restrict__ cursor)
{
    const int g = blockIdx.x * SCAN_B + threadIdx.x;
    if (g >= NSITES) return;
    const int st = starts[g] + blockoff[blockIdx.x];
    starts[g] = st;
    cursor[g] = st;
}

// ---------------------------------------------------------------------------
// Pass 3: fill CSR. csr[pos] = (k<<19) | in_idx   (in_idx < 2^19, k < 2^5)
// ---------------------------------------------------------------------------
__global__ __launch_bounds__(256) void fill_kernel(
    const int* __restrict__ rules_in, const int* __restrict__ rules_out,
    int* __restrict__ cursor, int* __restrict__ csr)
{
    const int k = blockIdx.y;
    const int r = blockIdx.x * blockDim.x + threadIdx.x;
    if (r >= RPAIR) return;
    const int p = k * RPAIR + r;
    const int o = rules_out[p];
    const int in = rules_in[p];
    const int pos = atomicAdd(cursor + o, 1);
    csr[pos] = (k << 19) | in;
}

// ---------------------------------------------------------------------------
// Pass 4: gather. One thread per output row; full 16x16 matvec per entry,
// all 27 weights staged in LDS; row written exactly once. No fp atomics.
// ---------------------------------------------------------------------------
__device__ inline void fma4(float4& a, float s, const float4 w) {
    a.x = fmaf(s, w.x, a.x);
    a.y = fmaf(s, w.y, a.y);
    a.z = fmaf(s, w.z, a.z);
    a.w = fmaf(s, w.w, a.w);
}

__global__ __launch_bounds__(512) void gather_kernel(
    const float* __restrict__ features,
    const float* __restrict__ weight,
    const float* __restrict__ bias,
    const int*   __restrict__ starts,
    const int*   __restrict__ counts,
    const int*   __restrict__ csr,
    float*       __restrict__ out)
{
    __shared__ __align__(16) float wlds[KOFF * WSTRIDE];
    const int tid = threadIdx.x;
    // stage all 27 weight matrices ([k][cin][cout] -> [k][WSTRIDE])
    for (int idx = tid; idx < KOFF * 256; idx += 512) {
        const int k = idx >> 8;
        wlds[k * WSTRIDE + (idx & 255)] = weight[idx];
    }
    __syncthreads();

    const int row = blockIdx.x * blockDim.x + tid;
    if (row >= NSITES) return;

    const float4* b4 = (const float4*)bias;
    float4 a0 = b4[0], a1 = b4[1], a2 = b4[2], a3 = b4[3];

    const int start = starts[row];
    const int n     = counts[row];

    for (int i = 0; i < n; ++i) {
        const int v  = csr[start + i];
        const int k  = v >> 19;
        const int in = v & 0x7FFFF;

        const float4* f4 = (const float4*)(features + (size_t)in * CIN);
        const float4 f0 = f4[0], f1 = f4[1], f2 = f4[2], f3 = f4[3];

        const float4* w4 = (const float4*)(wlds + k * WSTRIDE);
#define CSTEP(fc, c)                       \
        {                                  \
            fma4(a0, (fc), w4[(c) * 4 + 0]); \
            fma4(a1, (fc), w4[(c) * 4 + 1]); \
            fma4(a2, (fc), w4[(c) * 4 + 2]); \
            fma4(a3, (fc), w4[(c) * 4 + 3]); \
        }
        CSTEP(f0.x,  0) CSTEP(f0.y,  1) CSTEP(f0.z,  2) CSTEP(f0.w,  3)
        CSTEP(f1.x,  4) CSTEP(f1.y,  5) CSTEP(f1.z,  6) CSTEP(f1.w,  7)
        CSTEP(f2.x,  8) CSTEP(f2.y,  9) CSTEP(f2.z, 10) CSTEP(f2.w, 11)
        CSTEP(f3.x, 12) CSTEP(f3.y, 13) CSTEP(f3.z, 14) CSTEP(f3.w, 15)
#undef CSTEP
    }

    float4* o = (float4*)(out + (size_t)row * COUT);
    o[0] = a0; o[1] = a1; o[2] = a2; o[3] = a3;
}

// ---------------------------------------------------------------------------
extern "C" void kernel_launch(void* const* d_in, const int* in_sizes, int n_in,
                              void* d_out, int out_size, void* d_ws, size_t ws_size,
                              hipStream_t stream)
{
    const float* features  = (const float*)d_in[0];
    const float* weight    = (const float*)d_in[1];
    const float* bias      = (const float*)d_in[2];
    const int*   rules_in  = (const int*)d_in[3];
    const int*   rules_out = (const int*)d_in[4];
    float*       out       = (float*)d_out;

    int* ws       = (int*)d_ws;
    int* counts   = ws;
    int* starts   = ws + NSITES;
    int* cursor   = ws + 2 * NSITES;
    int* blocksum = ws + 3 * NSITES;
    int* blockoff = ws + 3 * NSITES + 512;
    int* csr      = ws + 3 * NSITES + 1024;

    // counts = 0 (ws is re-poisoned 0xAA before every launch)
    hipMemsetAsync(counts, 0, NSITES * sizeof(int), stream);

    dim3 gridKR((RPAIR + 255) / 256, KOFF);
    histogram_kernel<<<gridKR, 256, 0, stream>>>(rules_out, counts);

    scan_blocks_kernel<<<NBLK, SCAN_B, 0, stream>>>(counts, starts, blocksum);
    scan_totals_kernel<<<1, SCAN_B, 0, stream>>>(blocksum, blockoff);
    add_base_kernel<<<NBLK, SCAN_B, 0, stream>>>(starts, blockoff, cursor);

    fill_kernel<<<gridKR, 256, 0, stream>>>(rules_in, rules_out, cursor, csr);

    gather_kernel<<<(NSITES + 511) / 512, 512, 0, stream>>>(
        features, weight, bias, starts, counts, csr, out);
}